// Round 1
// baseline (79.470 us; speedup 1.0000x reference)
//
#include <hip/hip_runtime.h>
#include <math.h>

#define BATCH 4
#define NTOK 4096
#define ATTN_D 16
#define KNODES 64                       // Chebyshev nodes (= wave width)
#define BLOCK 1024
#define NWAVES (BLOCK / 64)             // 16
#define M_PER_WAVE (NTOK / NWAVES)      // 256

// out[b,n] = cvo * g(a_n),  a_n = 0.25*cqk*x[b,n]
// g(a) = sum_m x_m e^{a x_m} / sum_m e^{a x_m}
// Evaluate g exactly at 64 Chebyshev nodes spanning the exact range of a,
// then evaluate all 4096 rows via the degree-63 Chebyshev interpolant.
__global__ __launch_bounds__(BLOCK) void attn_cheb_kernel(
    const float* __restrict__ x,     // [B, N]
    const float* __restrict__ wq,    // [16]
    const float* __restrict__ wk,    // [16]
    const float* __restrict__ wv,    // [16]
    const float* __restrict__ wout,  // [16]
    float* __restrict__ out)         // [B, N]
{
    __shared__ float sx[NTOK];                   // 16 KB: x[b,:]
    __shared__ float psum[NWAVES][KNODES][2];    // 8 KB: per-wave node partials
    __shared__ float sred[2 * NWAVES];           // max/min partials
    __shared__ float cx[KNODES];                 // Chebyshev coefficients

    const int tid  = threadIdx.x;
    const int lane = tid & 63;
    const int wave = tid >> 6;
    const int b    = blockIdx.x;

    const float* xb = x + b * NTOK;

    // ---- stage x[b,:] into LDS (one float4 per thread), track max/min ----
    float4 v = ((const float4*)xb)[tid];
    ((float4*)sx)[tid] = v;
    float vmax = fmaxf(fmaxf(v.x, v.y), fmaxf(v.z, v.w));
    float vmin = fminf(fminf(v.x, v.y), fminf(v.z, v.w));
    #pragma unroll
    for (int off = 32; off > 0; off >>= 1) {
        vmax = fmaxf(vmax, __shfl_xor(vmax, off));
        vmin = fminf(vmin, __shfl_xor(vmin, off));
    }
    if (lane == 0) { sred[wave] = vmax; sred[NWAVES + wave] = vmin; }
    __syncthreads();
    vmax = sred[0]; vmin = sred[NWAVES];
    #pragma unroll
    for (int w = 1; w < NWAVES; ++w) {
        vmax = fmaxf(vmax, sred[w]);
        vmin = fminf(vmin, sred[NWAVES + w]);
    }

    // ---- collapsed weight dots (uniform scalar loads) ----
    float cqk = 0.f, cvo = 0.f;
    #pragma unroll
    for (int d = 0; d < ATTN_D; ++d) {
        cqk = fmaf(wq[d], wk[d], cqk);
        cvo = fmaf(wv[d], wout[d], cvo);
    }

    const float s   = 0.25f * cqk;               // scale=1/sqrt(16), tau=1
    const float alo = fminf(s * vmin, s * vmax); // exact range of a over rows
    const float ahi = fmaxf(s * vmin, s * vmax);
    const float ctr = 0.5f * (alo + ahi);
    const float hw  = fmaxf(0.5f * (ahi - alo), 1e-30f);

    const float PI_OVER = 3.14159265358979323846f / (2.0f * KNODES); // pi/128
    const float LOG2E   = 1.4426950408889634f;

    // this lane's Chebyshev (1st kind) node: a_j = ctr + hw*cos((2j+1)pi/128)
    const float an = fmaf(hw, cosf((float)(2 * lane + 1) * PI_OVER), ctr);
    const float a2 = an * LOG2E;
    const float M2 = ((an >= 0.f) ? an * vmax : an * vmin) * LOG2E; // max of an*x

    // ---- phase 1: node sums. wave w covers m in [256w, 256w+256) ----
    float S0 = 0.f, S1 = 0.f;
    const float4* s4 = (const float4*)sx;
    #pragma unroll 4
    for (int i = 0; i < M_PER_WAVE / 4; ++i) {
        float4 xm4 = s4[wave * (M_PER_WAVE / 4) + i];   // LDS broadcast
        #pragma unroll
        for (int c = 0; c < 4; ++c) {
            float xm = (c == 0) ? xm4.x : (c == 1) ? xm4.y : (c == 2) ? xm4.z : xm4.w;
            float e = __builtin_amdgcn_exp2f(fmaf(a2, xm, -M2));
            S0 += e;
            S1 = fmaf(xm, e, S1);
        }
    }
    psum[wave][lane][0] = S0;
    psum[wave][lane][1] = S1;
    __syncthreads();

    // ---- reduce partials -> g at nodes (wave 0, lane = node) ----
    if (wave == 0) {
        float t0 = 0.f, t1 = 0.f;
        #pragma unroll
        for (int w = 0; w < NWAVES; ++w) {
            t0 += psum[w][lane][0];
            t1 += psum[w][lane][1];
        }
        psum[0][lane][0] = t1 / t0;   // e^{-M} factor cancels in the ratio
    }
    __syncthreads();

    // ---- DCT: c_k = (2/K) sum_j g_j cos(k(2j+1)pi/(2K)), k = lane ----
    // integer angle reduction mod 256 keeps the cos argument exact;
    // fp64 accumulation keeps coefficient noise below 1e-6.
    if (wave == 0) {
        double acc = 0.0;
        for (int j = 0; j < KNODES; ++j) {
            int u = ((2 * j + 1) * lane) & (4 * KNODES - 1);   // mod 256
            acc += (double)(psum[0][j][0] * cosf((float)u * PI_OVER));
        }
        cx[lane] = (float)(acc * (2.0 / (double)KNODES));
    }
    __syncthreads();

    // ---- phase 2: rows 4*tid .. 4*tid+3, Clenshaw evaluation ----
    const float ihw = 1.0f / hw;
    float4 xr = s4[tid];
    float tt[4], t2[4];
    #pragma unroll
    for (int i = 0; i < 4; ++i) {
        float xi = (i == 0) ? xr.x : (i == 1) ? xr.y : (i == 2) ? xr.z : xr.w;
        tt[i] = fmaf(s, xi, -ctr) * ihw;   // t in [-1,1] by construction
        t2[i] = 2.0f * tt[i];
    }
    float b1v[4] = {0.f, 0.f, 0.f, 0.f};
    float b2v[4] = {0.f, 0.f, 0.f, 0.f};
    for (int k = KNODES - 1; k >= 1; --k) {
        float ck = cx[k];                  // LDS broadcast, amortized x4 rows
        #pragma unroll
        for (int i = 0; i < 4; ++i) {
            float b0 = fmaf(t2[i], b1v[i], ck - b2v[i]);
            b2v[i] = b1v[i];
            b1v[i] = b0;
        }
    }
    const float c0h = 0.5f * cx[0];
    float4 o;
    float* op = &o.x;
    #pragma unroll
    for (int i = 0; i < 4; ++i) {
        op[i] = cvo * fmaf(tt[i], b1v[i], c0h - b2v[i]);
    }
    ((float4*)(out + b * NTOK))[tid] = o;
}

extern "C" void kernel_launch(void* const* d_in, const int* in_sizes, int n_in,
                              void* d_out, int out_size, void* d_ws, size_t ws_size,
                              hipStream_t stream) {
    const float* x    = (const float*)d_in[0];
    const float* wq   = (const float*)d_in[1];
    const float* wk   = (const float*)d_in[2];
    const float* wv   = (const float*)d_in[3];
    const float* wout = (const float*)d_in[4];
    float* out = (float*)d_out;

    attn_cheb_kernel<<<dim3(BATCH), dim3(BLOCK), 0, stream>>>(
        x, wq, wk, wv, wout, out);
}

// Round 2
// 71.293 us; speedup vs baseline: 1.1147x; 1.1147x over previous
//
#include <hip/hip_runtime.h>
#include <math.h>

#define BATCH 4
#define NTOK 4096
#define ATTN_D 16
#define KNODES 256              // Chebyshev nodes: rho^-256 ~ 1e-11 interp error
#define NODES_PER_GRP 4
#define NGRP (KNODES / NODES_PER_GRP)   // 64 groups -> 256 blocks total
#define BLK 256
#define WS_G 64                 // float offset of g[] in workspace (stats use 0..15)

// out[b,n] = cvo * g_b(x[b,n]),  g_b(y) = sum_m x_m e^{s y x_m} / sum_m e^{s y x_m}
// Kernel A: evaluate g_b exactly at 256 Chebyshev nodes over [xmin, xmax].
// Kernel B: barycentric interpolation of g_b at each row value (stable, no DCT).

__global__ __launch_bounds__(BLK) void attn_nodes_kernel(
    const float* __restrict__ x,     // [B, N]
    const float* __restrict__ wq,    // [16]
    const float* __restrict__ wk,    // [16]
    const float* __restrict__ wv,    // [16]
    const float* __restrict__ wout,  // [16]
    float* __restrict__ ws)          // workspace
{
    __shared__ float sx[NTOK];                     // 16 KB
    __shared__ float sred[8];
    __shared__ float part[4][NODES_PER_GRP][2];

    const int tid  = threadIdx.x;
    const int lane = tid & 63;
    const int wave = tid >> 6;
    const int b    = blockIdx.x >> 6;              // / NGRP
    const int grp  = blockIdx.x & (NGRP - 1);

    const float* xb = x + b * NTOK;

    // ---- stage x[b,:] into LDS, track max/min (identical code in every block
    //      of this kernel -> bit-identical ctr/hw/s across blocks) ----
    float vmax = -INFINITY, vmin = INFINITY;
    const float4* x4 = (const float4*)xb;
    float4* s4 = (float4*)sx;
    #pragma unroll
    for (int i = 0; i < 4; ++i) {
        float4 v = x4[tid + i * BLK];
        s4[tid + i * BLK] = v;
        vmax = fmaxf(vmax, fmaxf(fmaxf(v.x, v.y), fmaxf(v.z, v.w)));
        vmin = fminf(vmin, fminf(fminf(v.x, v.y), fminf(v.z, v.w)));
    }
    #pragma unroll
    for (int off = 32; off > 0; off >>= 1) {
        vmax = fmaxf(vmax, __shfl_xor(vmax, off));
        vmin = fminf(vmin, __shfl_xor(vmin, off));
    }
    if (lane == 0) { sred[wave] = vmax; sred[4 + wave] = vmin; }
    __syncthreads();
    vmax = fmaxf(fmaxf(sred[0], sred[1]), fmaxf(sred[2], sred[3]));
    vmin = fminf(fminf(sred[4], sred[5]), fminf(sred[6], sred[7]));

    float cqk = 0.f, cvo = 0.f;
    #pragma unroll
    for (int d = 0; d < ATTN_D; ++d) {
        cqk = fmaf(wq[d], wk[d], cqk);
        cvo = fmaf(wv[d], wout[d], cvo);
    }
    const float s   = 0.25f * cqk;                 // scale=1/sqrt(16), tau=1
    const float ctr = 0.5f * (vmax + vmin);
    const float hw  = fmaxf(0.5f * (vmax - vmin), 1e-30f);

    if (grp == 0 && tid == 0)
        ((float4*)ws)[b] = make_float4(ctr, hw, s, cvo);

    const float PI_2K  = 3.14159265358979323846f / (2.0f * KNODES);
    const float LOG2E  = 1.4426950408889634f;

    // this block's 4 nodes (in x-space)
    float a2[NODES_PER_GRP], M2[NODES_PER_GRP];
    float S0[NODES_PER_GRP], S1[NODES_PER_GRP];
    #pragma unroll
    for (int jj = 0; jj < NODES_PER_GRP; ++jj) {
        int j = grp * NODES_PER_GRP + jj;
        float tj = fmaf(hw, cosf((float)(2 * j + 1) * PI_2K), ctr);
        float a  = s * tj;
        a2[jj] = a * LOG2E;
        M2[jj] = fmaxf(a * vmax, a * vmin) * LOG2E;   // max of a*x_m, base 2
        S0[jj] = 0.f;
        S1[jj] = 0.f;
    }

    // ---- node sums: 16 m-values per thread x 4 nodes = 64 exps/lane ----
    #pragma unroll
    for (int i = 0; i < 4; ++i) {
        float4 v = s4[tid + i * BLK];
        #pragma unroll
        for (int c = 0; c < 4; ++c) {
            float xm = (c == 0) ? v.x : (c == 1) ? v.y : (c == 2) ? v.z : v.w;
            #pragma unroll
            for (int jj = 0; jj < NODES_PER_GRP; ++jj) {
                float e = __builtin_amdgcn_exp2f(fmaf(a2[jj], xm, -M2[jj]));
                S0[jj] += e;
                S1[jj] = fmaf(xm, e, S1[jj]);
            }
        }
    }

    // ---- reduce: wave shuffle, then cross-wave in LDS ----
    #pragma unroll
    for (int jj = 0; jj < NODES_PER_GRP; ++jj) {
        float t0 = S0[jj], t1 = S1[jj];
        #pragma unroll
        for (int off = 32; off > 0; off >>= 1) {
            t0 += __shfl_xor(t0, off);
            t1 += __shfl_xor(t1, off);
        }
        if (lane == 0) { part[wave][jj][0] = t0; part[wave][jj][1] = t1; }
    }
    __syncthreads();
    if (tid < NODES_PER_GRP) {
        float t0 = part[0][tid][0] + part[1][tid][0] + part[2][tid][0] + part[3][tid][0];
        float t1 = part[0][tid][1] + part[1][tid][1] + part[2][tid][1] + part[3][tid][1];
        ws[WS_G + b * KNODES + grp * NODES_PER_GRP + tid] = t1 / t0; // e^{-M} cancels
    }
}

__global__ __launch_bounds__(BLK) void attn_eval_kernel(
    const float* __restrict__ x,     // [B, N]
    const float* __restrict__ ws,    // stats + g at nodes
    float* __restrict__ out)         // [B, N]
{
    __shared__ float4 snode[KNODES];               // {t_j, w_j, w_j*g_j, 0}

    const int tid = threadIdx.x;
    const int b   = blockIdx.x >> 4;
    const int rb  = blockIdx.x & 15;

    float4 st = ((const float4*)ws)[b];            // {ctr, hw, s, cvo}
    const float ctr = st.x, hw = st.y, cvo = st.w;

    const float PI_2K = 3.14159265358979323846f / (2.0f * KNODES);

    // build node table: thread j owns node j (barycentric weights for
    // Chebyshev points of the 1st kind: w_j = (-1)^j sin(theta_j))
    {
        float theta = (float)(2 * tid + 1) * PI_2K;
        float tj = fmaf(hw, cosf(theta), ctr);     // same expr as kernel A
        float w  = sinf(theta);
        if (tid & 1) w = -w;
        float gj = ws[WS_G + b * KNODES + tid];
        snode[tid] = make_float4(tj, w, w * gj, 0.f);
    }
    __syncthreads();

    const int row = rb * BLK + tid;
    const float t = x[b * NTOK + row];

    float num = 0.f, den = 0.f;
    #pragma unroll 4
    for (int j = 0; j < KNODES; ++j) {
        float4 nd = snode[j];                      // LDS broadcast
        float d  = t - nd.x;
        float ad = fabsf(d);
        d = (ad < 1e-30f) ? 1e-30f : d;            // t==t_j: term dominates -> g_j
        float r = __builtin_amdgcn_rcpf(d);
        den = fmaf(nd.y, r, den);
        num = fmaf(nd.z, r, num);
    }
    out[b * NTOK + row] = cvo * (num / den);
}

extern "C" void kernel_launch(void* const* d_in, const int* in_sizes, int n_in,
                              void* d_out, int out_size, void* d_ws, size_t ws_size,
                              hipStream_t stream) {
    const float* x    = (const float*)d_in[0];
    const float* wq   = (const float*)d_in[1];
    const float* wk   = (const float*)d_in[2];
    const float* wv   = (const float*)d_in[3];
    const float* wout = (const float*)d_in[4];
    float* out = (float*)d_out;
    float* ws  = (float*)d_ws;

    attn_nodes_kernel<<<dim3(BATCH * NGRP), dim3(BLK), 0, stream>>>(
        x, wq, wk, wv, wout, ws);
    attn_eval_kernel<<<dim3(BATCH * 16), dim3(BLK), 0, stream>>>(
        x, ws, out);
}